// Round 12
// baseline (401.973 us; speedup 1.0000x reference)
//
#include <hip/hip_runtime.h>
#include <math.h>

#define D 128
#define CAP 80     // bucket slots per node (incoming only; self-loop folded into k_agg)
#define CNTS 16    // cnt padded: one counter per 64B line

typedef __attribute__((ext_vector_type(8))) short short8;
typedef __attribute__((ext_vector_type(4))) float float4v;
typedef __attribute__((ext_vector_type(4))) _Float16 half4v;
typedef __attribute__((ext_vector_type(8))) _Float16 half8v;
typedef __attribute__((ext_vector_type(4))) int int4v;

__device__ __forceinline__ unsigned short f2bf(float x) {
    unsigned u = __float_as_uint(x);
    u += ((u >> 16) & 1u) + 0x7fffu;          // RNE
    return (unsigned short)(u >> 16);
}
__device__ __forceinline__ float bf2f(unsigned short h) {
    return __uint_as_float((unsigned)h << 16);
}

// ---------------- prep: W pack (3 layers) + cnt zero, one launch ---------------------
// wpack tile (ct,kt): lane holds W[k=kt*32+(lane>>4)*8+j][n=ct*16+(lane&15)], j=0..7

__global__ void k_prep(const float* __restrict__ W0, const float* __restrict__ W1,
                       const float* __restrict__ W2, unsigned short* __restrict__ whi,
                       unsigned short* __restrict__ wlo, int* __restrict__ cnt, int N) {
    int id = blockIdx.x * blockDim.x + threadIdx.x;
    if (id < 6144) {
        int l = id >> 11;
        int id2 = id & 2047;
        const float* W = (l == 0) ? W0 : (l == 1) ? W1 : W2;
        int lane = id2 & 63;
        int tile = id2 >> 6;          // ct*4 + kt
        int kt = tile & 3;
        int ct = tile >> 2;
        int k0 = kt * 32 + (lane >> 4) * 8;
        int n  = ct * 16 + (lane & 15);
        size_t base = (size_t)l * 16384 + (size_t)id2 * 8;
        for (int j = 0; j < 8; j++) {
            float w = W[(k0 + j) * D + n];
            unsigned short h = f2bf(w);
            whi[base + j] = h;
            wlo[base + j] = f2bf(w - bf2f(h));
        }
    } else {
        int i = id - 6144;
        if (i < N * CNTS) cnt[i] = 0;
    }
}

// ---------------- bucket fill: STANDALONE, R13 config (76us operating point) ---------
// History: R12 occ 2x -> null. R13 cnt-pad + NT -> null. R14 1-pass no-partition ->
// regressed (cross-XCD writeback churn). R15/R16 fusion with gemm-0 -> both regressed
// (wave-pool dilution + shared transaction queues). VERDICT: fill runs ALONE in this
// exact config (XCD-partitioned blockIdx&7, int4 dst loads, padded cnt, grid 2048).

__global__ __launch_bounds__(256) void k_fill(const int* __restrict__ ei, int E, int N,
                                              int* __restrict__ cnt,
                                              int* __restrict__ bucket) {
    int part = blockIdx.x & 7;
    int slice = blockIdx.x >> 3;
    int nsl = gridDim.x >> 3;
    int lo = (int)((long long)N * part >> 3);
    int hi = (int)((long long)N * (part + 1) >> 3);
    const int4v* dst4 = (const int4v*)(ei + E);
    int nv = E >> 2;
    for (int i = slice * 256 + (int)threadIdx.x; i < nv; i += nsl * 256) {
        int4v d4 = __builtin_nontemporal_load(&dst4[i]);
        int base = i << 2;
        if (d4.x >= lo && d4.x < hi) {
            int s_ = __builtin_nontemporal_load(&ei[base + 0]);
            int p = atomicAdd(&cnt[d4.x << 4], 1);
            if (p < CAP) bucket[(size_t)d4.x * CAP + p] = s_;
        }
        if (d4.y >= lo && d4.y < hi) {
            int s_ = __builtin_nontemporal_load(&ei[base + 1]);
            int p = atomicAdd(&cnt[d4.y << 4], 1);
            if (p < CAP) bucket[(size_t)d4.y * CAP + p] = s_;
        }
        if (d4.z >= lo && d4.z < hi) {
            int s_ = __builtin_nontemporal_load(&ei[base + 2]);
            int p = atomicAdd(&cnt[d4.z << 4], 1);
            if (p < CAP) bucket[(size_t)d4.z * CAP + p] = s_;
        }
        if (d4.w >= lo && d4.w < hi) {
            int s_ = __builtin_nontemporal_load(&ei[base + 3]);
            int p = atomicAdd(&cnt[d4.w << 4], 1);
            if (p < CAP) bucket[(size_t)d4.w * CAP + p] = s_;
        }
    }
    int tail = E & 3;
    if (slice == 0 && (int)threadIdx.x < tail) {
        int e = (nv << 2) + threadIdx.x;
        int d_ = (ei + E)[e];
        if (d_ >= lo && d_ < hi) {
            int s_ = ei[e];
            int p = atomicAdd(&cnt[d_ << 4], 1);
            if (p < CAP) bucket[(size_t)d_ * CAP + p] = s_;
        }
    }
}

// ---------------- A-row -> bf16 hi/lo B-operand fragments (optional expmap0) ---------
// lanes m, m+16, m+32, m+48 share row rg; EXP reduces across the 4 quads (2 shuffles).
// fp16 input (layers 1,2) is captured EXACTLY by the bf16 hi/lo split.

template <bool EXP, typename AT>
__device__ __forceinline__ void prep_frags(const AT* __restrict__ A, int rg, int N,
                                           int quad, short8* bhi, short8* blo) {
    bool valid = rg < N;
    const AT* arow = &A[(size_t)(valid ? rg : 0) * D];
    float af[32];
#pragma unroll
    for (int kt = 0; kt < 4; kt++) {
        int k0 = kt * 32 + quad * 8;
        if constexpr (sizeof(AT) == 4) {
            float4 x0 = valid ? *(const float4*)&arow[k0]     : make_float4(0.f, 0.f, 0.f, 0.f);
            float4 x1 = valid ? *(const float4*)&arow[k0 + 4] : make_float4(0.f, 0.f, 0.f, 0.f);
            af[kt * 8 + 0] = x0.x; af[kt * 8 + 1] = x0.y; af[kt * 8 + 2] = x0.z; af[kt * 8 + 3] = x0.w;
            af[kt * 8 + 4] = x1.x; af[kt * 8 + 5] = x1.y; af[kt * 8 + 6] = x1.z; af[kt * 8 + 7] = x1.w;
        } else {
            half8v h8 = (half8v){0, 0, 0, 0, 0, 0, 0, 0};
            if (valid) h8 = *(const half8v*)&arow[k0];
#pragma unroll
            for (int j = 0; j < 8; j++) af[kt * 8 + j] = (float)h8[j];
        }
    }
    if (EXP) {
        float ss = 0.f;
#pragma unroll
        for (int q = 0; q < 32; q++) ss += af[q] * af[q];
        ss += __shfl_xor(ss, 16, 64);
        ss += __shfl_xor(ss, 32, 64);
        float n = fmaxf(sqrtf(ss), 1e-15f);
        float sc = tanhf(n) / n;
#pragma unroll
        for (int q = 0; q < 32; q++) af[q] *= sc;
    }
#pragma unroll
    for (int kt = 0; kt < 4; kt++) {
#pragma unroll
        for (int j = 0; j < 8; j++) {
            float v = af[kt * 8 + j];
            unsigned short h = f2bf(v);
            bhi[kt][j] = (short)h;
            blo[kt][j] = (short)f2bf(v - bf2f(h));
        }
    }
}

// ---------------- MFMA GEMM, operand-swapped, 128 rows/block, 2 row-groups -----------
// R22: 3-MFMA split (drop wlo.blo cross term, ~2^-18 relative ~ 1e-6 abs -- far below
// the 6.1e-5 fp16-H floor). Cuts the MFMA stream 25%; probes whether gemm's ~46us
// (vs ~6us memory roofline) is matrix-pipe-issue-bound at 2 waves/SIMD.
// 391 blocks, W staged ONCE per block, amortized over two 64-row groups.
// Group-0 A fragments prepped BEFORE the barrier (A latency overlaps staging drain).
// C/D: col=node, row=4 consec features. H stored fp16 (R11). A templated fp32/fp16.

template <bool EXP, typename AT>
__global__ __launch_bounds__(256) void k_gemm(const AT* __restrict__ A,
                                              const unsigned short* __restrict__ Whi,
                                              const unsigned short* __restrict__ Wlo,
                                              const float* __restrict__ avS,
                                              const float* __restrict__ avD,
                                              _Float16* __restrict__ H,
                                              float* __restrict__ sA,
                                              float* __restrict__ dA, int N) {
    __shared__ unsigned short WshHi[16384];   // 32 KB
    __shared__ unsigned short WshLo[16384];   // 32 KB
    int t = threadIdx.x;
    int wv = t >> 6, lane = t & 63, quad = lane >> 4, m = lane & 15;

    {   // issue W hi/lo staging (fully coalesced)
        const uint4* gh = (const uint4*)Whi;
        const uint4* gl = (const uint4*)Wlo;
        uint4* sh = (uint4*)WshHi;
        uint4* sl = (uint4*)WshLo;
#pragma unroll
        for (int i = 0; i < 8; i++) {
            sh[i * 256 + t] = gh[i * 256 + t];
            sl[i * 256 + t] = gl[i * 256 + t];
        }
    }

    // group-0 A fragments before the barrier
    int rgBase = blockIdx.x * 128 + wv * 16 + m;
    short8 bhi[4], blo[4];
    prep_frags<EXP, AT>(A, rgBase, N, quad, bhi, blo);

    __syncthreads();

#pragma unroll
    for (int g = 0; g < 2; g++) {
        int rg = rgBase + g * 64;
        if (g == 1) prep_frags<EXP, AT>(A, rg, N, quad, bhi, blo);
        bool valid = rg < N;

        float4v acc[8];
#pragma unroll
        for (int ct = 0; ct < 8; ct++) acc[ct] = (float4v){0.f, 0.f, 0.f, 0.f};

#pragma unroll
        for (int kt = 0; kt < 4; kt++) {
#pragma unroll
            for (int ct = 0; ct < 8; ct++) {
                int wofs = (((ct << 2) | kt) * 64 + lane) * 8;
                short8 whi = *(const short8*)&WshHi[wofs];
                short8 wlo = *(const short8*)&WshLo[wofs];
                acc[ct] = __builtin_amdgcn_mfma_f32_16x16x32_bf16(whi, blo[kt], acc[ct], 0, 0, 0);
                acc[ct] = __builtin_amdgcn_mfma_f32_16x16x32_bf16(wlo, bhi[kt], acc[ct], 0, 0, 0);
                acc[ct] = __builtin_amdgcn_mfma_f32_16x16x32_bf16(whi, bhi[kt], acc[ct], 0, 0, 0);
            }
        }

        if (valid) {
#pragma unroll
            for (int ct = 0; ct < 8; ct++) {
                half4v o;
                o[0] = (_Float16)acc[ct][0];
                o[1] = (_Float16)acc[ct][1];
                o[2] = (_Float16)acc[ct][2];
                o[3] = (_Float16)acc[ct][3];
                *(half4v*)&H[(size_t)rg * D + ct * 16 + quad * 4] = o;
            }
        }

        float ps = 0.f, pd = 0.f;
#pragma unroll
        for (int ct = 0; ct < 8; ct++) {
            int fb = ct * 16 + quad * 4;
            float4 as4 = *(const float4*)&avS[fb];
            float4 ad4 = *(const float4*)&avD[fb];
            ps += acc[ct][0] * as4.x + acc[ct][1] * as4.y + acc[ct][2] * as4.z + acc[ct][3] * as4.w;
            pd += acc[ct][0] * ad4.x + acc[ct][1] * ad4.y + acc[ct][2] * ad4.z + acc[ct][3] * ad4.w;
        }
        ps += __shfl_xor(ps, 16, 64);
        ps += __shfl_xor(ps, 32, 64);
        pd += __shfl_xor(pd, 16, 64);
        pd += __shfl_xor(pd, 32, 64);
        if (quad == 0 && valid) {
            sA[rg] = ps;
            dA[rg] = pd;
        }
    }
}

// ---------------- fused softmax + aggregation: one wave per dst ----------------------
// R21: 16-edge select-first main loop (2x per-wave MLP) -> 60->55us/layer, rate
// 138->150 GT/s. R22: software-pipeline the csr index loads -- prefetch next
// iteration's q BEFORE consuming current H rows, removing one serial L2 round-trip
// per iteration (~2-3 iters/node). +16 VGPR, still far under the 64-VGPR cliff.

template <bool ACT>
__global__ __launch_bounds__(256) void k_agg(const _Float16* __restrict__ H,
                                             const float* __restrict__ sA,
                                             const float* __restrict__ dA,
                                             const int* __restrict__ cnt,
                                             const int* __restrict__ bucket,
                                             const float* __restrict__ bias,
                                             void* __restrict__ out, int N) {
    int lane = threadIdx.x & 63;
    int node = blockIdx.x * 4 + (threadIdx.x >> 6);
    if (node >= N) return;
    int deg   = __builtin_amdgcn_readfirstlane(cnt[node << 4]);
    if (deg > CAP) deg = CAP;
    int start = node * CAP;
    int end   = start + deg;
    const int* csr = bucket;
    const half4v* Hv = (const half4v*)H;      // row = 32 half4 chunks
    float di  = dA[node];
    int half  = lane >> 5;
    int hq    = lane & 31;                    // half4 chunk index within row
    int cq    = hq * 4;                       // float feature index (bias / out)

    float ax = 0.f, ay = 0.f, az = 0.f, aw = 0.f;
    float den = 0.f;
    int j = start;

    // 16-edge main loop: select-first + pipelined csr prefetch
    int4v q0, q1, q2, q3;
    if (j + 16 <= end) {
        q0 = *(const int4v*)&csr[j];
        q1 = *(const int4v*)&csr[j + 4];
        q2 = *(const int4v*)&csr[j + 8];
        q3 = *(const int4v*)&csr[j + 12];
    }
    for (; j + 16 <= end; ) {
        int r0 = half ? q0.y : q0.x;
        int r1 = half ? q0.w : q0.z;
        int r2 = half ? q1.y : q1.x;
        int r3 = half ? q1.w : q1.z;
        int r4 = half ? q2.y : q2.x;
        int r5 = half ? q2.w : q2.z;
        int r6 = half ? q3.y : q3.x;
        int r7 = half ? q3.w : q3.z;
        float e0 = sA[r0], e1 = sA[r1], e2 = sA[r2], e3 = sA[r3];
        float e4 = sA[r4], e5 = sA[r5], e6 = sA[r6], e7 = sA[r7];
        half4v h0 = Hv[(size_t)r0 * 32 + hq];
        half4v h1 = Hv[(size_t)r1 * 32 + hq];
        half4v h2 = Hv[(size_t)r2 * 32 + hq];
        half4v h3 = Hv[(size_t)r3 * 32 + hq];
        half4v h4 = Hv[(size_t)r4 * 32 + hq];
        half4v h5 = Hv[(size_t)r5 * 32 + hq];
        half4v h6 = Hv[(size_t)r6 * 32 + hq];
        half4v h7 = Hv[(size_t)r7 * 32 + hq];
        j += 16;
        if (j + 16 <= end) {      // prefetch next iteration's indices (overlaps consume)
            q0 = *(const int4v*)&csr[j];
            q1 = *(const int4v*)&csr[j + 4];
            q2 = *(const int4v*)&csr[j + 8];
            q3 = *(const int4v*)&csr[j + 12];
        }
        e0 += di; e1 += di; e2 += di; e3 += di;
        e4 += di; e5 += di; e6 += di; e7 += di;
        e0 = (e0 > 0.f) ? e0 : 0.2f * e0;
        e1 = (e1 > 0.f) ? e1 : 0.2f * e1;
        e2 = (e2 > 0.f) ? e2 : 0.2f * e2;
        e3 = (e3 > 0.f) ? e3 : 0.2f * e3;
        e4 = (e4 > 0.f) ? e4 : 0.2f * e4;
        e5 = (e5 > 0.f) ? e5 : 0.2f * e5;
        e6 = (e6 > 0.f) ? e6 : 0.2f * e6;
        e7 = (e7 > 0.f) ? e7 : 0.2f * e7;
        float p0 = __expf(e0), p1 = __expf(e1), p2 = __expf(e2), p3 = __expf(e3);
        float p4 = __expf(e4), p5 = __expf(e5), p6 = __expf(e6), p7 = __expf(e7);
        den += ((p0 + p1) + (p2 + p3)) + ((p4 + p5) + (p6 + p7));
        ax += p0 * (float)h0[0] + p1 * (float)h1[0] + p2 * (float)h2[0] + p3 * (float)h3[0]
            + p4 * (float)h4[0] + p5 * (float)h5[0] + p6 * (float)h6[0] + p7 * (float)h7[0];
        ay += p0 * (float)h0[1] + p1 * (float)h1[1] + p2 * (float)h2[1] + p3 * (float)h3[1]
            + p4 * (float)h4[1] + p5 * (float)h5[1] + p6 * (float)h6[1] + p7 * (float)h7[1];
        az += p0 * (float)h0[2] + p1 * (float)h1[2] + p2 * (float)h2[2] + p3 * (float)h3[2]
            + p4 * (float)h4[2] + p5 * (float)h5[2] + p6 * (float)h6[2] + p7 * (float)h7[2];
        aw += p0 * (float)h0[3] + p1 * (float)h1[3] + p2 * (float)h2[3] + p3 * (float)h3[3]
            + p4 * (float)h4[3] + p5 * (float)h5[3] + p6 * (float)h6[3] + p7 * (float)h7[3];
    }
    if (j + 8 <= end) {
        int4v t0 = *(const int4v*)&csr[j];
        int4v t1 = *(const int4v*)&csr[j + 4];
        int r0 = half ? t0.y : t0.x;
        int r1 = half ? t0.w : t0.z;
        int r2 = half ? t1.y : t1.x;
        int r3 = half ? t1.w : t1.z;
        float e0 = sA[r0], e1 = sA[r1], e2 = sA[r2], e3 = sA[r3];
        half4v h0 = Hv[(size_t)r0 * 32 + hq];
        half4v h1 = Hv[(size_t)r1 * 32 + hq];
        half4v h2 = Hv[(size_t)r2 * 32 + hq];
        half4v h3 = Hv[(size_t)r3 * 32 + hq];
        e0 += di; e1 += di; e2 += di; e3 += di;
        e0 = (e0 > 0.f) ? e0 : 0.2f * e0;
        e1 = (e1 > 0.f) ? e1 : 0.2f * e1;
        e2 = (e2 > 0.f) ? e2 : 0.2f * e2;
        e3 = (e3 > 0.f) ? e3 : 0.2f * e3;
        float p0 = __expf(e0), p1 = __expf(e1), p2 = __expf(e2), p3 = __expf(e3);
        den += (p0 + p1) + (p2 + p3);
        ax += p0 * (float)h0[0] + p1 * (float)h1[0] + p2 * (float)h2[0] + p3 * (float)h3[0];
        ay += p0 * (float)h0[1] + p1 * (float)h1[1] + p2 * (float)h2[1] + p3 * (float)h3[1];
        az += p0 * (float)h0[2] + p1 * (float)h1[2] + p2 * (float)h2[2] + p3 * (float)h3[2];
        aw += p0 * (float)h0[3] + p1 * (float)h1[3] + p2 * (float)h2[3] + p3 * (float)h3[3];
        j += 8;
    }
    if (j + 4 <= end) {
        int4v t0 = *(const int4v*)&csr[j];
        int r0 = half ? t0.y : t0.x;
        int r1 = half ? t0.w : t0.z;
        float e0 = sA[r0], e1 = sA[r1];
        half4v h0 = Hv[(size_t)r0 * 32 + hq];
        half4v h1 = Hv[(size_t)r1 * 32 + hq];
        e0 += di; e1 += di;
        e0 = (e0 > 0.f) ? e0 : 0.2f * e0;
        e1 = (e1 > 0.f) ? e1 : 0.2f * e1;
        float p0 = __expf(e0), p1 = __expf(e1);
        den += p0 + p1;
        ax += p0 * (float)h0[0] + p1 * (float)h1[0];
        ay += p0 * (float)h0[1] + p1 * (float)h1[1];
        az += p0 * (float)h0[2] + p1 * (float)h1[2];
        aw += p0 * (float)h0[3] + p1 * (float)h1[3];
        j += 4;
    }
    if (j + 2 <= end) {
        int s0 = csr[j + 0], s1 = csr[j + 1];
        int r0 = half ? s1 : s0;
        float e0 = sA[r0] + di;
        half4v h0 = Hv[(size_t)r0 * 32 + hq];
        e0 = (e0 > 0.f) ? e0 : 0.2f * e0;
        float p0 = __expf(e0);
        den += p0;
        ax += p0 * (float)h0[0]; ay += p0 * (float)h0[1];
        az += p0 * (float)h0[2]; aw += p0 * (float)h0[3];
        j += 2;
    }
    if (j < end && half == 0) {
        int s0 = csr[j];
        float e0 = sA[s0] + di;
        e0 = (e0 > 0.f) ? e0 : 0.2f * e0;
        float p0 = __expf(e0);
        den += p0;
        half4v h0 = Hv[(size_t)s0 * 32 + hq];
        ax += p0 * (float)h0[0]; ay += p0 * (float)h0[1];
        az += p0 * (float)h0[2]; aw += p0 * (float)h0[3];
    }

    // self-loop (half 0 only; merged by the cross-half reduction below)
    if (half == 0) {
        float e0 = sA[node] + di;
        e0 = (e0 > 0.f) ? e0 : 0.2f * e0;
        float p0 = __expf(e0);
        den += p0;
        half4v h0 = Hv[(size_t)node * 32 + hq];
        ax += p0 * (float)h0[0]; ay += p0 * (float)h0[1];
        az += p0 * (float)h0[2]; aw += p0 * (float)h0[3];
    }

    ax  += __shfl_xor(ax, 32, 64);
    ay  += __shfl_xor(ay, 32, 64);
    az  += __shfl_xor(az, 32, 64);
    aw  += __shfl_xor(aw, 32, 64);
    den += __shfl_xor(den, 32, 64);

    if (half == 0) {
        float iv = 1.f / den;
        float4 b4 = *(const float4*)&bias[cq];
        float vx = ax * iv + b4.x;
        float vy = ay * iv + b4.y;
        float vz = az * iv + b4.z;
        float vw = aw * iv + b4.w;
        if (ACT) {
            vx = 2.f * tanhf(vx);
            vy = 2.f * tanhf(vy);
            vz = 2.f * tanhf(vz);
            vw = 2.f * tanhf(vw);
            half4v o;
            o[0] = (_Float16)vx; o[1] = (_Float16)vy;
            o[2] = (_Float16)vz; o[3] = (_Float16)vw;
            *(half4v*)&((_Float16*)out)[(size_t)node * D + cq] = o;
        } else {
            *(float4*)&((float*)out)[(size_t)node * D + cq] = make_float4(vx, vy, vz, vw);
        }
    }
}

// ---------------- launch ----------------

extern "C" void kernel_launch(void* const* d_in, const int* in_sizes, int n_in,
                              void* d_out, int out_size, void* d_ws, size_t ws_size,
                              hipStream_t stream) {
    const int N = in_sizes[0] / D;
    const int E = in_sizes[1] / 2;
    const float* x = (const float*)d_in[0];
    const int* ei = (const int*)d_in[1];
    const float* Wm[3] = {(const float*)d_in[2], (const float*)d_in[6], (const float*)d_in[10]};
    const float* aS[3] = {(const float*)d_in[3], (const float*)d_in[7], (const float*)d_in[11]};
    const float* aD[3] = {(const float*)d_in[4], (const float*)d_in[8], (const float*)d_in[12]};
    const float* bb[3] = {(const float*)d_in[5], (const float*)d_in[9], (const float*)d_in[13]};

    char* ws = (char*)d_ws;
    size_t off = 0;
    auto alloc = [&](size_t bytes) -> void* {
        void* p = ws + off;
        off = (off + bytes + 511) & ~(size_t)511;
        return p;
    };
    _Float16*  bufA   = (_Float16*)alloc((size_t)N * D * 2);   // fp16 activations
    _Float16*  bufB   = (_Float16*)alloc((size_t)N * D * 2);   // fp16 H
    float*     sArr   = (float*)alloc((size_t)N * 4);
    float*     dArr   = (float*)alloc((size_t)N * 4);
    int*       cnt    = (int*)alloc((size_t)N * CNTS * 4);
    int*       bucket = (int*)alloc((size_t)N * CAP * 4);
    unsigned short* whiB = (unsigned short*)alloc((size_t)3 * D * D * 2);
    unsigned short* wloB = (unsigned short*)alloc((size_t)3 * D * D * 2);
    (void)ws_size; (void)n_in; (void)out_size;

    k_prep<<<(6144 + N * CNTS + 255) / 256, 256, 0, stream>>>(Wm[0], Wm[1], Wm[2],
                                                              whiB, wloB, cnt, N);
    k_fill<<<2048, 256, 0, stream>>>(ei, E, N, cnt, bucket);

    const int gemmBlocks = (N + 127) / 128;
    for (int l = 0; l < 3; l++) {
        const unsigned short* whi = whiB + (size_t)l * 16384;
        const unsigned short* wlo = wloB + (size_t)l * 16384;
        if (l == 0) {
            k_gemm<true, float><<<gemmBlocks, 256, 0, stream>>>(x, whi, wlo, aS[0], aD[0],
                                                                bufB, sArr, dArr, N);
        } else {
            k_gemm<false, _Float16><<<gemmBlocks, 256, 0, stream>>>(bufA, whi, wlo,
                                                                    aS[l], aD[l],
                                                                    bufB, sArr, dArr, N);
        }
        if (l < 2) {
            k_agg<true><<<(N + 3) / 4, 256, 0, stream>>>(bufB, sArr, dArr, cnt, bucket,
                                                         bb[l], bufA, N);
        } else {
            k_agg<false><<<(N + 3) / 4, 256, 0, stream>>>(bufB, sArr, dArr, cnt, bucket,
                                                          bb[l], d_out, N);
        }
    }
}

// Round 13
// 386.775 us; speedup vs baseline: 1.0393x; 1.0393x over previous
//
#include <hip/hip_runtime.h>
#include <math.h>

#define D 128
#define CAP 80     // bucket slots per node (incoming only; self-loop folded into k_agg)
#define CNTS 16    // cnt padded: one counter per 64B line

typedef __attribute__((ext_vector_type(8))) short short8;
typedef __attribute__((ext_vector_type(4))) float float4v;
typedef __attribute__((ext_vector_type(4))) _Float16 half4v;
typedef __attribute__((ext_vector_type(8))) _Float16 half8v;
typedef __attribute__((ext_vector_type(4))) int int4v;

__device__ __forceinline__ unsigned short f2bf(float x) {
    unsigned u = __float_as_uint(x);
    u += ((u >> 16) & 1u) + 0x7fffu;          // RNE
    return (unsigned short)(u >> 16);
}
__device__ __forceinline__ float bf2f(unsigned short h) {
    return __uint_as_float((unsigned)h << 16);
}

// ---------------- prep: W pack (3 layers) + cnt zero, one launch ---------------------
// wpack tile (ct,kt): lane holds W[k=kt*32+(lane>>4)*8+j][n=ct*16+(lane&15)], j=0..7

__global__ void k_prep(const float* __restrict__ W0, const float* __restrict__ W1,
                       const float* __restrict__ W2, unsigned short* __restrict__ whi,
                       unsigned short* __restrict__ wlo, int* __restrict__ cnt, int N) {
    int id = blockIdx.x * blockDim.x + threadIdx.x;
    if (id < 6144) {
        int l = id >> 11;
        int id2 = id & 2047;
        const float* W = (l == 0) ? W0 : (l == 1) ? W1 : W2;
        int lane = id2 & 63;
        int tile = id2 >> 6;          // ct*4 + kt
        int kt = tile & 3;
        int ct = tile >> 2;
        int k0 = kt * 32 + (lane >> 4) * 8;
        int n  = ct * 16 + (lane & 15);
        size_t base = (size_t)l * 16384 + (size_t)id2 * 8;
        for (int j = 0; j < 8; j++) {
            float w = W[(k0 + j) * D + n];
            unsigned short h = f2bf(w);
            whi[base + j] = h;
            wlo[base + j] = f2bf(w - bf2f(h));
        }
    } else {
        int i = id - 6144;
        if (i < N * CNTS) cnt[i] = 0;
    }
}

// ---------------- bucket fill: STANDALONE, R13 config (76us operating point) ---------
// History: R12 occ 2x -> null. R13 cnt-pad + NT -> null. R14 1-pass no-partition ->
// regressed (cross-XCD writeback churn). R15/R16 fusion with gemm-0 -> both regressed
// (wave-pool dilution + shared transaction queues). VERDICT: fill runs ALONE in this
// exact config (XCD-partitioned blockIdx&7, int4 dst loads, padded cnt, grid 2048).

__global__ __launch_bounds__(256) void k_fill(const int* __restrict__ ei, int E, int N,
                                              int* __restrict__ cnt,
                                              int* __restrict__ bucket) {
    int part = blockIdx.x & 7;
    int slice = blockIdx.x >> 3;
    int nsl = gridDim.x >> 3;
    int lo = (int)((long long)N * part >> 3);
    int hi = (int)((long long)N * (part + 1) >> 3);
    const int4v* dst4 = (const int4v*)(ei + E);
    int nv = E >> 2;
    for (int i = slice * 256 + (int)threadIdx.x; i < nv; i += nsl * 256) {
        int4v d4 = __builtin_nontemporal_load(&dst4[i]);
        int base = i << 2;
        if (d4.x >= lo && d4.x < hi) {
            int s_ = __builtin_nontemporal_load(&ei[base + 0]);
            int p = atomicAdd(&cnt[d4.x << 4], 1);
            if (p < CAP) bucket[(size_t)d4.x * CAP + p] = s_;
        }
        if (d4.y >= lo && d4.y < hi) {
            int s_ = __builtin_nontemporal_load(&ei[base + 1]);
            int p = atomicAdd(&cnt[d4.y << 4], 1);
            if (p < CAP) bucket[(size_t)d4.y * CAP + p] = s_;
        }
        if (d4.z >= lo && d4.z < hi) {
            int s_ = __builtin_nontemporal_load(&ei[base + 2]);
            int p = atomicAdd(&cnt[d4.z << 4], 1);
            if (p < CAP) bucket[(size_t)d4.z * CAP + p] = s_;
        }
        if (d4.w >= lo && d4.w < hi) {
            int s_ = __builtin_nontemporal_load(&ei[base + 3]);
            int p = atomicAdd(&cnt[d4.w << 4], 1);
            if (p < CAP) bucket[(size_t)d4.w * CAP + p] = s_;
        }
    }
    int tail = E & 3;
    if (slice == 0 && (int)threadIdx.x < tail) {
        int e = (nv << 2) + threadIdx.x;
        int d_ = (ei + E)[e];
        if (d_ >= lo && d_ < hi) {
            int s_ = ei[e];
            int p = atomicAdd(&cnt[d_ << 4], 1);
            if (p < CAP) bucket[(size_t)d_ * CAP + p] = s_;
        }
    }
}

// ---------------- A-row -> bf16 hi/lo B-operand fragments (optional expmap0) ---------
// lanes m, m+16, m+32, m+48 share row rg; EXP reduces across the 4 quads (2 shuffles).
// fp16 input (layers 1,2) is captured EXACTLY by the bf16 hi/lo split.

template <bool EXP, typename AT>
__device__ __forceinline__ void prep_frags(const AT* __restrict__ A, int rg, int N,
                                           int quad, short8* bhi, short8* blo) {
    bool valid = rg < N;
    const AT* arow = &A[(size_t)(valid ? rg : 0) * D];
    float af[32];
#pragma unroll
    for (int kt = 0; kt < 4; kt++) {
        int k0 = kt * 32 + quad * 8;
        if constexpr (sizeof(AT) == 4) {
            float4 x0 = valid ? *(const float4*)&arow[k0]     : make_float4(0.f, 0.f, 0.f, 0.f);
            float4 x1 = valid ? *(const float4*)&arow[k0 + 4] : make_float4(0.f, 0.f, 0.f, 0.f);
            af[kt * 8 + 0] = x0.x; af[kt * 8 + 1] = x0.y; af[kt * 8 + 2] = x0.z; af[kt * 8 + 3] = x0.w;
            af[kt * 8 + 4] = x1.x; af[kt * 8 + 5] = x1.y; af[kt * 8 + 6] = x1.z; af[kt * 8 + 7] = x1.w;
        } else {
            half8v h8 = (half8v){0, 0, 0, 0, 0, 0, 0, 0};
            if (valid) h8 = *(const half8v*)&arow[k0];
#pragma unroll
            for (int j = 0; j < 8; j++) af[kt * 8 + j] = (float)h8[j];
        }
    }
    if (EXP) {
        float ss = 0.f;
#pragma unroll
        for (int q = 0; q < 32; q++) ss += af[q] * af[q];
        ss += __shfl_xor(ss, 16, 64);
        ss += __shfl_xor(ss, 32, 64);
        float n = fmaxf(sqrtf(ss), 1e-15f);
        float sc = tanhf(n) / n;
#pragma unroll
        for (int q = 0; q < 32; q++) af[q] *= sc;
    }
#pragma unroll
    for (int kt = 0; kt < 4; kt++) {
#pragma unroll
        for (int j = 0; j < 8; j++) {
            float v = af[kt * 8 + j];
            unsigned short h = f2bf(v);
            bhi[kt][j] = (short)h;
            blo[kt][j] = (short)f2bf(v - bf2f(h));
        }
    }
}

// ---------------- MFMA GEMM, operand-swapped, 128 rows/block, 2 row-groups (R19) -----
// R22 falsified: dropping the wlo.blo MFMA (3-MFMA split, bundled with agg prefetch)
// regressed ~+14us total -- the 4-MFMA chain gives the scheduler more independent ops
// to pack against LDS-read latency. KEEP 4-MFMA.
// 391 blocks, W staged ONCE per block, amortized over two 64-row groups.
// Group-0 A fragments prepped BEFORE the barrier (A latency overlaps staging drain).
// C/D: col=node, row=4 consec features. bf16x4 split = fp32-grade accuracy.
// H stored fp16 (R11). Input A templated: fp32 layer 0, fp16 layers 1,2.

template <bool EXP, typename AT>
__global__ __launch_bounds__(256) void k_gemm(const AT* __restrict__ A,
                                              const unsigned short* __restrict__ Whi,
                                              const unsigned short* __restrict__ Wlo,
                                              const float* __restrict__ avS,
                                              const float* __restrict__ avD,
                                              _Float16* __restrict__ H,
                                              float* __restrict__ sA,
                                              float* __restrict__ dA, int N) {
    __shared__ unsigned short WshHi[16384];   // 32 KB
    __shared__ unsigned short WshLo[16384];   // 32 KB
    int t = threadIdx.x;
    int wv = t >> 6, lane = t & 63, quad = lane >> 4, m = lane & 15;

    {   // issue W hi/lo staging (fully coalesced)
        const uint4* gh = (const uint4*)Whi;
        const uint4* gl = (const uint4*)Wlo;
        uint4* sh = (uint4*)WshHi;
        uint4* sl = (uint4*)WshLo;
#pragma unroll
        for (int i = 0; i < 8; i++) {
            sh[i * 256 + t] = gh[i * 256 + t];
            sl[i * 256 + t] = gl[i * 256 + t];
        }
    }

    // group-0 A fragments before the barrier
    int rgBase = blockIdx.x * 128 + wv * 16 + m;
    short8 bhi[4], blo[4];
    prep_frags<EXP, AT>(A, rgBase, N, quad, bhi, blo);

    __syncthreads();

#pragma unroll
    for (int g = 0; g < 2; g++) {
        int rg = rgBase + g * 64;
        if (g == 1) prep_frags<EXP, AT>(A, rg, N, quad, bhi, blo);
        bool valid = rg < N;

        float4v acc[8];
#pragma unroll
        for (int ct = 0; ct < 8; ct++) acc[ct] = (float4v){0.f, 0.f, 0.f, 0.f};

#pragma unroll
        for (int kt = 0; kt < 4; kt++) {
#pragma unroll
            for (int ct = 0; ct < 8; ct++) {
                int wofs = (((ct << 2) | kt) * 64 + lane) * 8;
                short8 whi = *(const short8*)&WshHi[wofs];
                short8 wlo = *(const short8*)&WshLo[wofs];
                acc[ct] = __builtin_amdgcn_mfma_f32_16x16x32_bf16(wlo, blo[kt], acc[ct], 0, 0, 0);
                acc[ct] = __builtin_amdgcn_mfma_f32_16x16x32_bf16(whi, blo[kt], acc[ct], 0, 0, 0);
                acc[ct] = __builtin_amdgcn_mfma_f32_16x16x32_bf16(wlo, bhi[kt], acc[ct], 0, 0, 0);
                acc[ct] = __builtin_amdgcn_mfma_f32_16x16x32_bf16(whi, bhi[kt], acc[ct], 0, 0, 0);
            }
        }

        if (valid) {
#pragma unroll
            for (int ct = 0; ct < 8; ct++) {
                half4v o;
                o[0] = (_Float16)acc[ct][0];
                o[1] = (_Float16)acc[ct][1];
                o[2] = (_Float16)acc[ct][2];
                o[3] = (_Float16)acc[ct][3];
                *(half4v*)&H[(size_t)rg * D + ct * 16 + quad * 4] = o;
            }
        }

        float ps = 0.f, pd = 0.f;
#pragma unroll
        for (int ct = 0; ct < 8; ct++) {
            int fb = ct * 16 + quad * 4;
            float4 as4 = *(const float4*)&avS[fb];
            float4 ad4 = *(const float4*)&avD[fb];
            ps += acc[ct][0] * as4.x + acc[ct][1] * as4.y + acc[ct][2] * as4.z + acc[ct][3] * as4.w;
            pd += acc[ct][0] * ad4.x + acc[ct][1] * ad4.y + acc[ct][2] * ad4.z + acc[ct][3] * ad4.w;
        }
        ps += __shfl_xor(ps, 16, 64);
        ps += __shfl_xor(ps, 32, 64);
        pd += __shfl_xor(pd, 16, 64);
        pd += __shfl_xor(pd, 32, 64);
        if (quad == 0 && valid) {
            sA[rg] = ps;
            dA[rg] = pd;
        }
    }
}

// ---------------- fused softmax + aggregation: one wave per dst ----------------------
// R21 form (best measured): 16-edge select-first main loop -- each half picks its 8
// rows, then issues 8 sA + 8 H-row loads back-to-back before any use (2x per-wave
// MLP vs 8-edge). R22's loop-carried csr prefetch regressed; KEEP the straight loop.
// Wall: ~150 GT/s random-request rate + per-wave MLP; 5 tx/edge.

template <bool ACT>
__global__ __launch_bounds__(256) void k_agg(const _Float16* __restrict__ H,
                                             const float* __restrict__ sA,
                                             const float* __restrict__ dA,
                                             const int* __restrict__ cnt,
                                             const int* __restrict__ bucket,
                                             const float* __restrict__ bias,
                                             void* __restrict__ out, int N) {
    int lane = threadIdx.x & 63;
    int node = blockIdx.x * 4 + (threadIdx.x >> 6);
    if (node >= N) return;
    int deg   = __builtin_amdgcn_readfirstlane(cnt[node << 4]);
    if (deg > CAP) deg = CAP;
    int start = node * CAP;
    int end   = start + deg;
    const int* csr = bucket;
    const half4v* Hv = (const half4v*)H;      // row = 32 half4 chunks
    float di  = dA[node];
    int half  = lane >> 5;
    int hq    = lane & 31;                    // half4 chunk index within row
    int cq    = hq * 4;                       // float feature index (bias / out)

    float ax = 0.f, ay = 0.f, az = 0.f, aw = 0.f;
    float den = 0.f;
    int j = start;

    // 16-edge main loop: select-first, issue 8 sA + 8 H loads per half up front
    for (; j + 16 <= end; j += 16) {
        int4v q0 = *(const int4v*)&csr[j];
        int4v q1 = *(const int4v*)&csr[j + 4];
        int4v q2 = *(const int4v*)&csr[j + 8];
        int4v q3 = *(const int4v*)&csr[j + 12];
        int r0 = half ? q0.y : q0.x;
        int r1 = half ? q0.w : q0.z;
        int r2 = half ? q1.y : q1.x;
        int r3 = half ? q1.w : q1.z;
        int r4 = half ? q2.y : q2.x;
        int r5 = half ? q2.w : q2.z;
        int r6 = half ? q3.y : q3.x;
        int r7 = half ? q3.w : q3.z;
        float e0 = sA[r0], e1 = sA[r1], e2 = sA[r2], e3 = sA[r3];
        float e4 = sA[r4], e5 = sA[r5], e6 = sA[r6], e7 = sA[r7];
        half4v h0 = Hv[(size_t)r0 * 32 + hq];
        half4v h1 = Hv[(size_t)r1 * 32 + hq];
        half4v h2 = Hv[(size_t)r2 * 32 + hq];
        half4v h3 = Hv[(size_t)r3 * 32 + hq];
        half4v h4 = Hv[(size_t)r4 * 32 + hq];
        half4v h5 = Hv[(size_t)r5 * 32 + hq];
        half4v h6 = Hv[(size_t)r6 * 32 + hq];
        half4v h7 = Hv[(size_t)r7 * 32 + hq];
        e0 += di; e1 += di; e2 += di; e3 += di;
        e4 += di; e5 += di; e6 += di; e7 += di;
        e0 = (e0 > 0.f) ? e0 : 0.2f * e0;
        e1 = (e1 > 0.f) ? e1 : 0.2f * e1;
        e2 = (e2 > 0.f) ? e2 : 0.2f * e2;
        e3 = (e3 > 0.f) ? e3 : 0.2f * e3;
        e4 = (e4 > 0.f) ? e4 : 0.2f * e4;
        e5 = (e5 > 0.f) ? e5 : 0.2f * e5;
        e6 = (e6 > 0.f) ? e6 : 0.2f * e6;
        e7 = (e7 > 0.f) ? e7 : 0.2f * e7;
        float p0 = __expf(e0), p1 = __expf(e1), p2 = __expf(e2), p3 = __expf(e3);
        float p4 = __expf(e4), p5 = __expf(e5), p6 = __expf(e6), p7 = __expf(e7);
        den += ((p0 + p1) + (p2 + p3)) + ((p4 + p5) + (p6 + p7));
        ax += p0 * (float)h0[0] + p1 * (float)h1[0] + p2 * (float)h2[0] + p3 * (float)h3[0]
            + p4 * (float)h4[0] + p5 * (float)h5[0] + p6 * (float)h6[0] + p7 * (float)h7[0];
        ay += p0 * (float)h0[1] + p1 * (float)h1[1] + p2 * (float)h2[1] + p3 * (float)h3[1]
            + p4 * (float)h4[1] + p5 * (float)h5[1] + p6 * (float)h6[1] + p7 * (float)h7[1];
        az += p0 * (float)h0[2] + p1 * (float)h1[2] + p2 * (float)h2[2] + p3 * (float)h3[2]
            + p4 * (float)h4[2] + p5 * (float)h5[2] + p6 * (float)h6[2] + p7 * (float)h7[2];
        aw += p0 * (float)h0[3] + p1 * (float)h1[3] + p2 * (float)h2[3] + p3 * (float)h3[3]
            + p4 * (float)h4[3] + p5 * (float)h5[3] + p6 * (float)h6[3] + p7 * (float)h7[3];
    }
    if (j + 8 <= end) {
        int4v q0 = *(const int4v*)&csr[j];
        int4v q1 = *(const int4v*)&csr[j + 4];
        int r0 = half ? q0.y : q0.x;
        int r1 = half ? q0.w : q0.z;
        int r2 = half ? q1.y : q1.x;
        int r3 = half ? q1.w : q1.z;
        float e0 = sA[r0], e1 = sA[r1], e2 = sA[r2], e3 = sA[r3];
        half4v h0 = Hv[(size_t)r0 * 32 + hq];
        half4v h1 = Hv[(size_t)r1 * 32 + hq];
        half4v h2 = Hv[(size_t)r2 * 32 + hq];
        half4v h3 = Hv[(size_t)r3 * 32 + hq];
        e0 += di; e1 += di; e2 += di; e3 += di;
        e0 = (e0 > 0.f) ? e0 : 0.2f * e0;
        e1 = (e1 > 0.f) ? e1 : 0.2f * e1;
        e2 = (e2 > 0.f) ? e2 : 0.2f * e2;
        e3 = (e3 > 0.f) ? e3 : 0.2f * e3;
        float p0 = __expf(e0), p1 = __expf(e1), p2 = __expf(e2), p3 = __expf(e3);
        den += (p0 + p1) + (p2 + p3);
        ax += p0 * (float)h0[0] + p1 * (float)h1[0] + p2 * (float)h2[0] + p3 * (float)h3[0];
        ay += p0 * (float)h0[1] + p1 * (float)h1[1] + p2 * (float)h2[1] + p3 * (float)h3[1];
        az += p0 * (float)h0[2] + p1 * (float)h1[2] + p2 * (float)h2[2] + p3 * (float)h3[2];
        aw += p0 * (float)h0[3] + p1 * (float)h1[3] + p2 * (float)h2[3] + p3 * (float)h3[3];
        j += 8;
    }
    if (j + 4 <= end) {
        int4v q0 = *(const int4v*)&csr[j];
        int r0 = half ? q0.y : q0.x;
        int r1 = half ? q0.w : q0.z;
        float e0 = sA[r0], e1 = sA[r1];
        half4v h0 = Hv[(size_t)r0 * 32 + hq];
        half4v h1 = Hv[(size_t)r1 * 32 + hq];
        e0 += di; e1 += di;
        e0 = (e0 > 0.f) ? e0 : 0.2f * e0;
        e1 = (e1 > 0.f) ? e1 : 0.2f * e1;
        float p0 = __expf(e0), p1 = __expf(e1);
        den += p0 + p1;
        ax += p0 * (float)h0[0] + p1 * (float)h1[0];
        ay += p0 * (float)h0[1] + p1 * (float)h1[1];
        az += p0 * (float)h0[2] + p1 * (float)h1[2];
        aw += p0 * (float)h0[3] + p1 * (float)h1[3];
        j += 4;
    }
    if (j + 2 <= end) {
        int s0 = csr[j + 0], s1 = csr[j + 1];
        int r0 = half ? s1 : s0;
        float e0 = sA[r0] + di;
        half4v h0 = Hv[(size_t)r0 * 32 + hq];
        e0 = (e0 > 0.f) ? e0 : 0.2f * e0;
        float p0 = __expf(e0);
        den += p0;
        ax += p0 * (float)h0[0]; ay += p0 * (float)h0[1];
        az += p0 * (float)h0[2]; aw += p0 * (float)h0[3];
        j += 2;
    }
    if (j < end && half == 0) {
        int s0 = csr[j];
        float e0 = sA[s0] + di;
        e0 = (e0 > 0.f) ? e0 : 0.2f * e0;
        float p0 = __expf(e0);
        den += p0;
        half4v h0 = Hv[(size_t)s0 * 32 + hq];
        ax += p0 * (float)h0[0]; ay += p0 * (float)h0[1];
        az += p0 * (float)h0[2]; aw += p0 * (float)h0[3];
    }

    // self-loop (half 0 only; merged by the cross-half reduction below)
    if (half == 0) {
        float e0 = sA[node] + di;
        e0 = (e0 > 0.f) ? e0 : 0.2f * e0;
        float p0 = __expf(e0);
        den += p0;
        half4v h0 = Hv[(size_t)node * 32 + hq];
        ax += p0 * (float)h0[0]; ay += p0 * (float)h0[1];
        az += p0 * (float)h0[2]; aw += p0 * (float)h0[3];
    }

    ax  += __shfl_xor(ax, 32, 64);
    ay  += __shfl_xor(ay, 32, 64);
    az  += __shfl_xor(az, 32, 64);
    aw  += __shfl_xor(aw, 32, 64);
    den += __shfl_xor(den, 32, 64);

    if (half == 0) {
        float iv = 1.f / den;
        float4 b4 = *(const float4*)&bias[cq];
        float vx = ax * iv + b4.x;
        float vy = ay * iv + b4.y;
        float vz = az * iv + b4.z;
        float vw = aw * iv + b4.w;
        if (ACT) {
            vx = 2.f * tanhf(vx);
            vy = 2.f * tanhf(vy);
            vz = 2.f * tanhf(vz);
            vw = 2.f * tanhf(vw);
            half4v o;
            o[0] = (_Float16)vx; o[1] = (_Float16)vy;
            o[2] = (_Float16)vz; o[3] = (_Float16)vw;
            *(half4v*)&((_Float16*)out)[(size_t)node * D + cq] = o;
        } else {
            *(float4*)&((float*)out)[(size_t)node * D + cq] = make_float4(vx, vy, vz, vw);
        }
    }
}

// ---------------- launch ----------------

extern "C" void kernel_launch(void* const* d_in, const int* in_sizes, int n_in,
                              void* d_out, int out_size, void* d_ws, size_t ws_size,
                              hipStream_t stream) {
    const int N = in_sizes[0] / D;
    const int E = in_sizes[1] / 2;
    const float* x = (const float*)d_in[0];
    const int* ei = (const int*)d_in[1];
    const float* Wm[3] = {(const float*)d_in[2], (const float*)d_in[6], (const float*)d_in[10]};
    const float* aS[3] = {(const float*)d_in[3], (const float*)d_in[7], (const float*)d_in[11]};
    const float* aD[3] = {(const float*)d_in[4], (const float*)d_in[8], (const float*)d_in[12]};
    const float* bb[3] = {(const float*)d_in[5], (const float*)d_in[9], (const float*)d_in[13]};

    char* ws = (char*)d_ws;
    size_t off = 0;
    auto alloc = [&](size_t bytes) -> void* {
        void* p = ws + off;
        off = (off + bytes + 511) & ~(size_t)511;
        return p;
    };
    _Float16*  bufA   = (_Float16*)alloc((size_t)N * D * 2);   // fp16 activations
    _Float16*  bufB   = (_Float16*)alloc((size_t)N * D * 2);   // fp16 H
    float*     sArr   = (float*)alloc((size_t)N * 4);
    float*     dArr   = (float*)alloc((size_t)N * 4);
    int*       cnt    = (int*)alloc((size_t)N * CNTS * 4);
    int*       bucket = (int*)alloc((size_t)N * CAP * 4);
    unsigned short* whiB = (unsigned short*)alloc((size_t)3 * D * D * 2);
    unsigned short* wloB = (unsigned short*)alloc((size_t)3 * D * D * 2);
    (void)ws_size; (void)n_in; (void)out_size;

    k_prep<<<(6144 + N * CNTS + 255) / 256, 256, 0, stream>>>(Wm[0], Wm[1], Wm[2],
                                                              whiB, wloB, cnt, N);
    k_fill<<<2048, 256, 0, stream>>>(ei, E, N, cnt, bucket);

    const int gemmBlocks = (N + 127) / 128;
    for (int l = 0; l < 3; l++) {
        const unsigned short* whi = whiB + (size_t)l * 16384;
        const unsigned short* wlo = wloB + (size_t)l * 16384;
        if (l == 0) {
            k_gemm<true, float><<<gemmBlocks, 256, 0, stream>>>(x, whi, wlo, aS[0], aD[0],
                                                                bufB, sArr, dArr, N);
        } else {
            k_gemm<false, _Float16><<<gemmBlocks, 256, 0, stream>>>(bufA, whi, wlo,
                                                                    aS[l], aD[l],
                                                                    bufB, sArr, dArr, N);
        }
        if (l < 2) {
            k_agg<true><<<(N + 3) / 4, 256, 0, stream>>>(bufB, sArr, dArr, cnt, bucket,
                                                         bb[l], bufA, N);
        } else {
            k_agg<false><<<(N + 3) / 4, 256, 0, stream>>>(bufB, sArr, dArr, cnt, bucket,
                                                          bb[l], d_out, N);
        }
    }
}